// Round 14
// baseline (283.908 us; speedup 1.0000x reference)
//
#include <hip/hip_runtime.h>
#include <hip/hip_bf16.h>

typedef __attribute__((ext_vector_type(8))) short s8v;   // 8 x bf16 bits
typedef __attribute__((ext_vector_type(4))) short s4v;
typedef __attribute__((ext_vector_type(4))) float f4v;

#define B_   8
#define T_   4096
#define C_   1024
#define HS_  64
#define K2_  2048

__device__ __forceinline__ int keep_of(int i) {
    // keep[i] for i in [0,2048): exact integer version of the reference formula
    if (i >= 1024) return 2048 + i;
    int d = 1023 - i;
    return 3071 - ((3 * d * d + 1023) >> 10);
}

__device__ __forceinline__ short bf16_bits(float f) {
    union { __hip_bfloat16 h; short s; } u;
    u.h = __float2bfloat16(f);
    return u.s;
}

// load 8 consecutive fp32, round to bf16, pack into an MFMA bf16 fragment half
__device__ __forceinline__ s8v cvt8f(const float* p) {
    const f4v a = *(const f4v*)p;
    const f4v b = *(const f4v*)(p + 4);
    s8v r;
    r[0] = bf16_bits(a[0]); r[1] = bf16_bits(a[1]);
    r[2] = bf16_bits(a[2]); r[3] = bf16_bits(a[3]);
    r[4] = bf16_bits(b[0]); r[5] = bf16_bits(b[1]);
    r[6] = bf16_bits(b[2]); r[7] = bf16_bits(b[3]);
    return r;
}

// async 16B global -> LDS (direct-to-shared DMA; no VGPR round trip)
__device__ __forceinline__ void gload_lds16(const void* g, void* l) {
    __builtin_amdgcn_global_load_lds(
        (__attribute__((address_space(1))) void*)(g),
        (__attribute__((address_space(3))) void*)(l), 16, 0, 0);
}

// ------------- Kernel W: one-shot fp32 -> bf16 conversion of Wq/Wk/Wv -------
__global__ __launch_bounds__(256) void wcvt_kernel(
    const float* __restrict__ Wq, const float* __restrict__ Wk,
    const float* __restrict__ Wv, short* __restrict__ Wb)
{
    const int idx = (blockIdx.x * 256 + threadIdx.x) * 8;   // 0..196600
    const int mat = idx >> 16;                              // 0,1,2
    const int off = idx & 65535;
    const float* src = (mat == 0) ? Wq : (mat == 1) ? Wk : Wv;
    *(s8v*)(Wb + idx) = cvt8f(src + off);
}

// ---------------- Kernel A: fused QKV projection (R11 version, reverted) ----
// Block = 64 token rows x 192 out-cols (Q|K|V), BK=64, 16 K-steps, 40KB LDS
// -> 4 blocks/CU; cross-block overlap hides the 2-barrier drain (m114).
// V output tiled [T/64][HS][64] per batch (contiguous 8KB per 64-token tile).
__global__ __launch_bounds__(256) void qkv_kernel(
    const float* __restrict__ x,
    const short* __restrict__ Wb,   // [192][1024] bf16 (Wq|Wk|Wv rows)
    const float* __restrict__ bq, const float* __restrict__ bk,
    const float* __restrict__ bv,
    __hip_bfloat16* __restrict__ Qo, __hip_bfloat16* __restrict__ Ko,
    __hip_bfloat16* __restrict__ Vt)
{
    __shared__ __align__(16) char smem[40960];
    float* xs  = (float*)smem;            // [64 rows][64 k] fp32, 256B rows
    short* wsm = (short*)(smem + 16384);  // [192 rows][64 k] bf16, 128B rows

    const int tid  = threadIdx.x;
    const int wave = tid >> 6;
    const int lane = tid & 63;
    const int l16  = lane & 15;
    const int quad = lane >> 4;
    const int row0 = blockIdx.x * 64;

    f4v acc[3][4];                        // [matrix][m-tile]
    #pragma unroll
    for (int m = 0; m < 3; ++m)
        #pragma unroll
        for (int mt = 0; mt < 4; ++mt) {
            acc[m][mt][0] = 0.f; acc[m][mt][1] = 0.f;
            acc[m][mt][2] = 0.f; acc[m][mt][3] = 0.f;
        }

    // staging geometry (lane-contiguous LDS dest; swizzle in global src)
    int xrow[4], xoff[4];
    #pragma unroll
    for (int i = 0; i < 4; ++i) {
        const int f = 256 * i + tid;
        xrow[i] = f >> 4;
        xoff[i] = ((f & 15) ^ (xrow[i] & 7)) * 4;    // floats
    }
    int wrow[6], woff[6];
    #pragma unroll
    for (int i = 0; i < 6; ++i) {
        const int f = 256 * i + tid;
        wrow[i] = f >> 3;
        woff[i] = ((f & 7) ^ (wrow[i] & 7)) * 8;     // shorts
    }

    for (int k0 = 0; k0 < C_; k0 += 64) {
        __syncthreads();                  // previous step's LDS reads done
        #pragma unroll
        for (int i = 0; i < 4; ++i)
            gload_lds16(x + (size_t)(row0 + xrow[i]) * C_ + k0 + xoff[i],
                        (char*)xs + (256 * i + tid) * 16);
        #pragma unroll
        for (int i = 0; i < 6; ++i)
            gload_lds16(Wb + (size_t)wrow[i] * C_ + k0 + woff[i],
                        (char*)wsm + (256 * i + tid) * 16);
        __syncthreads();                  // vmcnt(0) drain -> tiles visible

        #pragma unroll
        for (int kh = 0; kh < 2; ++kh) {
            // A fragments: 4 m-tiles, converted fp32->bf16 once per kh
            s8v a[4];
            #pragma unroll
            for (int mt = 0; mt < 4; ++mt) {
                const int r   = mt * 16 + l16;
                const int ch0 = kh * 8 + quad * 2;
                const float* p0 = xs + r * 64 + ((ch0    ) ^ (r & 7)) * 4;
                const float* p1 = xs + r * 64 + ((ch0 + 1) ^ (r & 7)) * 4;
                const f4v u = *(const f4v*)p0;
                const f4v v = *(const f4v*)p1;
                s8v af;
                af[0] = bf16_bits(u[0]); af[1] = bf16_bits(u[1]);
                af[2] = bf16_bits(u[2]); af[3] = bf16_bits(u[3]);
                af[4] = bf16_bits(v[0]); af[5] = bf16_bits(v[1]);
                af[6] = bf16_bits(v[2]); af[7] = bf16_bits(v[3]);
                a[mt] = af;
            }
            // B fragments + MFMA: 3 matrices
            #pragma unroll
            for (int m = 0; m < 3; ++m) {
                const int wr = m * 64 + wave * 16 + l16;     // W row
                const int ch = kh * 4 + quad;                // 16B chunk 0..7
                const s8v bf = *(const s8v*)(wsm + wr * 64 + ((ch ^ (wr & 7)) * 8));
                #pragma unroll
                for (int mt = 0; mt < 4; ++mt)
                    acc[m][mt] = __builtin_amdgcn_mfma_f32_16x16x32_bf16(a[mt], bf, acc[m][mt], 0, 0, 0);
            }
        }
    }

    // epilogue: C/D layout col = lane&15 (folded into wc), row = quad*4+reg
    const int wc = wave * 16 + l16;                  // output column 0..63
    const float bqv = bq[wc], bkv = bk[wc], bvv = bv[wc];
    #pragma unroll
    for (int mt = 0; mt < 4; ++mt) {
        const int rbase = row0 + mt * 16 + quad * 4; // global token row
        #pragma unroll
        for (int r = 0; r < 4; ++r) {
            Qo[(size_t)(rbase + r) * HS_ + wc] = __float2bfloat16(acc[0][mt][r] + bqv);
            Ko[(size_t)(rbase + r) * HS_ + wc] = __float2bfloat16(acc[1][mt][r] + bkv);
        }
        s4v vp;
        #pragma unroll
        for (int r = 0; r < 4; ++r) vp[r] = bf16_bits(acc[2][mt][r] + bvv);
        const int bb = rbase >> 12;                  // batch
        const int t  = rbase & (T_ - 1);             // token within batch
        // tiled V^T: [T/64 tiles][HS][64t], tile = contiguous 8KB
        *(s4v*)(Vt + (size_t)bb * HS_ * T_
                   + (size_t)(t & ~63) * HS_ + wc * 64 + (t & 63)) = vp;
    }
}

// ---------------- Kernel B: flash attention, merged-qb single sweep ---------
// Round 13: the two qb of a pair share ONE staging sweep. n1(qb=64+pp) >=
// n2(qb=63-pp) always, so one pass of ceil(n1/4) 256-t steps stages each K/V
// tile ONCE; K/V fragments loaded to registers once per tile and fed to BOTH
// qb's MFMA chains (qb2 gated by its own ntiles). Staged bytes & barriers
// x0.67 vs R11's sequential which-loop; sync structure identical to R11.
// Heavy pairs (large pp) dispatched first.
__global__ __launch_bounds__(256) void attn_kernel(
    const __hip_bfloat16* __restrict__ Qo,
    const __hip_bfloat16* __restrict__ Ko,
    const __hip_bfloat16* __restrict__ Vt,
    float* __restrict__ out)
{
    __shared__ __align__(16) char smem[73728];
    short* Ks = (short*)smem;                 // [256 t][64 d] swizzled, 32KB
    short* Vs = (short*)(smem + 32768);       // [4 tiles][64 d][64 t] swz, 32KB
    float* mL = (float*)smem;                 // epilogue overlay (Ks dead)
    float* mO = (float*)(smem + 256);

    const int b    = blockIdx.x & 7;          // XCD-affine batch
    const int pp   = 63 - (blockIdx.x >> 3);  // heavy pairs first
    const int tid  = threadIdx.x;
    const int wave = tid >> 6;
    const int lane = tid & 63;
    const int l16  = lane & 15;
    const int quad = lane >> 4;

    short* pw = (short*)(smem + 65536) + wave * 1024;   // wave-private P, 2KB

    const short* kb = (const short*)Ko + (size_t)b * T_ * HS_;
    const short* vb = (const short*)Vt + (size_t)b * HS_ * T_;

    // staging geometry (tid-const; global-source swizzle, linear LDS dest)
    int kgoff[8], vgoff[8];
    #pragma unroll
    for (int j = 0; j < 8; ++j) {
        const int ki = j * 256 + tid;         // 16B chunk index 0..2047
        const int kr = ki >> 3;               // K row (t) 0..255
        kgoff[j] = kr * 64 + (((tid & 7) ^ (kr & 7)) * 8);
        const int vs_ = ki >> 9;              // V sub-tile 0..3
        const int vd  = (ki & 511) >> 3;      // V row (d) 0..63
        vgoff[j] = (vs_ * 64 + vd) * 64 + (((tid & 7) ^ (vd & 7)) * 8);
    }

    const int qbs[2] = { 64 + pp, 63 - pp };  // qb1 (longer t-range), qb2

    // Q fragments for both qb (A-operand): m = lane&15, k = quad*8+j
    s8v aq[2][2];
    int keepr[2][4], kmin[2], ntl[2];
    #pragma unroll
    for (int e = 0; e < 2; ++e) {
        const int qb = qbs[e];
        const int qt = keep_of(qb * 16 + l16);
        const __hip_bfloat16* qrow = Qo + ((size_t)(b * T_ + qt)) * HS_;
        aq[e][0] = *(const s8v*)(qrow + quad * 8);
        aq[e][1] = *(const s8v*)(qrow + 32 + quad * 8);
        #pragma unroll
        for (int r = 0; r < 4; ++r) keepr[e][r] = keep_of(qb * 16 + quad * 4 + r);
        kmin[e] = keep_of(qb * 16);
        ntl[e]  = (keep_of(qb * 16 + 15) >> 6) + 1;   // 64-wide t tiles
    }
    const int nsteps = (ntl[0] + 3) >> 2;             // ntl[0] >= ntl[1]

    f4v accO[2][4];
    float l_p[2][4];
    #pragma unroll
    for (int e = 0; e < 2; ++e)
        #pragma unroll
        for (int j = 0; j < 4; ++j) {
            accO[e][j][0]=0.f; accO[e][j][1]=0.f; accO[e][j][2]=0.f; accO[e][j][3]=0.f;
            l_p[e][j] = 0.f;
        }

    for (int s = 0; s < nsteps; ++s) {
        const int t064 = s << 14;             // (s*256)*64 shorts

        __syncthreads();                      // prev step's LDS reads done
        #pragma unroll
        for (int j = 0; j < 8; ++j)
            gload_lds16(kb + t064 + kgoff[j], (char*)smem + (j * 256 + tid) * 16);
        #pragma unroll
        for (int j = 0; j < 8; ++j)
            gload_lds16(vb + t064 + vgoff[j], (char*)smem + 32768 + (j * 256 + tid) * 16);
        __syncthreads();                      // vmcnt(0) drain -> tiles visible

        const int ttg = s * 4 + wave;         // this wave's tile index
        if (ttg < ntl[0]) {
            const int t0 = ttg << 6;

            // ---- K/V fragments: read ONCE, feed both qb ----
            s8v bk0[4], bk1[4], bv0[4], bv1[4];
            #pragma unroll
            for (int j = 0; j < 4; ++j) {
                const int row = wave * 64 + j * 16 + l16;
                bk0[j] = *(const s8v*)(Ks + row * 64 + (((quad    ) ^ (row & 7)) * 8));
                bk1[j] = *(const s8v*)(Ks + row * 64 + (((quad + 4) ^ (row & 7)) * 8));
                const int rd = j * 16 + l16;
                bv0[j] = *(const s8v*)(Vs + wave * 4096 + rd * 64 + (((quad    ) ^ (rd & 7)) * 8));
                bv1[j] = *(const s8v*)(Vs + wave * 4096 + rd * 64 + (((quad + 4) ^ (rd & 7)) * 8));
            }

            #pragma unroll
            for (int e = 0; e < 2; ++e) {
                if (e == 1 && ttg >= ntl[1]) break;   // qb2 range done

                // ---- S = Q K^T ----
                f4v s4[4];
                #pragma unroll
                for (int jn = 0; jn < 4; ++jn) {
                    f4v z; z[0]=0.f; z[1]=0.f; z[2]=0.f; z[3]=0.f;
                    z = __builtin_amdgcn_mfma_f32_16x16x32_bf16(aq[e][0], bk0[jn], z, 0, 0, 0);
                    z = __builtin_amdgcn_mfma_f32_16x16x32_bf16(aq[e][1], bk1[jn], z, 0, 0, 0);
                    s4[jn] = z;
                }

                // p = valid ? exp(s/32) : 0 ; mask only on boundary tiles
                if (t0 + 63 <= kmin[e]) {     // fully valid (common)
                    #pragma unroll
                    for (int jn = 0; jn < 4; ++jn) {
                        const int t = jn * 16 + l16;
                        const int chunk = t >> 3;
                        #pragma unroll
                        for (int r = 0; r < 4; ++r) {
                            const float p = __expf(s4[jn][r] * 0.03125f);
                            l_p[e][r] += p;
                            const int m = quad * 4 + r;
                            pw[m * 64 + ((chunk ^ (m & 7)) * 8) + (t & 7)] = bf16_bits(p);
                        }
                    }
                } else {                      // boundary tile
                    #pragma unroll
                    for (int jn = 0; jn < 4; ++jn) {
                        const int t = jn * 16 + l16;
                        const int valid_t = t0 + t;
                        const int chunk = t >> 3;
                        #pragma unroll
                        for (int r = 0; r < 4; ++r) {
                            const float ex = __expf(s4[jn][r] * 0.03125f);
                            const float p = (valid_t <= keepr[e][r]) ? ex : 0.0f;
                            l_p[e][r] += p;
                            const int m = quad * 4 + r;
                            pw[m * 64 + ((chunk ^ (m & 7)) * 8) + (t & 7)] = bf16_bits(p);
                        }
                    }
                }
                const s8v ap0 = *(const s8v*)(pw + l16 * 64 + ((quad    ) ^ (l16 & 7)) * 8);
                const s8v ap1 = *(const s8v*)(pw + l16 * 64 + ((quad + 4) ^ (l16 & 7)) * 8);

                // ---- O += P V ----
                #pragma unroll
                for (int jd = 0; jd < 4; ++jd) {
                    accO[e][jd] = __builtin_amdgcn_mfma_f32_16x16x32_bf16(ap0, bv0[jd], accO[e][jd], 0, 0, 0);
                    accO[e][jd] = __builtin_amdgcn_mfma_f32_16x16x32_bf16(ap1, bv1[jd], accO[e][jd], 0, 0, 0);
                }
            }
        }
    }

    // ---- epilogue per qb: butterfly -> cross-wave merge -> normalize -> out
    #pragma unroll 1
    for (int e = 0; e < 2; ++e) {
        const int qb = qbs[e];
        #pragma unroll
        for (int off = 1; off < 16; off <<= 1)
            #pragma unroll
            for (int r = 0; r < 4; ++r) l_p[e][r] += __shfl_xor(l_p[e][r], off);

        __syncthreads();                      // K/V/P LDS (or prev mO) dead
        #pragma unroll
        for (int r = 0; r < 4; ++r) {
            const int row = quad * 4 + r;
            if (l16 == 0) mL[wave * 16 + row] = l_p[e][r];
            #pragma unroll
            for (int jd = 0; jd < 4; ++jd)
                mO[wave * 1024 + row * 64 + jd * 16 + l16] = accO[e][jd][r];
        }
        __syncthreads();

        {
            const int row = tid >> 4;         // 0..15
            const int col = (tid & 15) * 4;   // 0..60
            float L = 0.f;
            #pragma unroll
            for (int w = 0; w < 4; ++w) L += mL[w * 16 + row];
            const float inv = 1.0f / L;
            f4v o; o[0]=0.f; o[1]=0.f; o[2]=0.f; o[3]=0.f;
            #pragma unroll
            for (int w = 0; w < 4; ++w) {
                const f4v ow = *(const f4v*)(mO + w * 1024 + row * 64 + col);
                #pragma unroll
                for (int j = 0; j < 4; ++j) o[j] += ow[j];
            }
            #pragma unroll
            for (int j = 0; j < 4; ++j) o[j] *= inv;
            *(f4v*)(out + ((size_t)(b * K2_ + qb * 16 + row)) * HS_ + col) = o;
        }
    }
}

extern "C" void kernel_launch(void* const* d_in, const int* in_sizes, int n_in,
                              void* d_out, int out_size, void* d_ws, size_t ws_size,
                              hipStream_t stream) {
    (void)in_sizes; (void)n_in; (void)out_size; (void)ws_size;
    const float* x  = (const float*)d_in[0];
    const float* Wq = (const float*)d_in[1];
    const float* bq = (const float*)d_in[2];
    const float* Wk = (const float*)d_in[3];
    const float* bk = (const float*)d_in[4];
    const float* Wv = (const float*)d_in[5];
    const float* bv = (const float*)d_in[6];

    __hip_bfloat16* Qo = (__hip_bfloat16*)d_ws;                       // 4 MB
    __hip_bfloat16* Ko = Qo + (size_t)B_ * T_ * HS_;                  // 4 MB
    __hip_bfloat16* Vt = Ko + (size_t)B_ * T_ * HS_;                  // 4 MB (tiled)
    short*          Wb = (short*)(Vt + (size_t)B_ * HS_ * T_);        // 384 KB
    float* o = (float*)d_out;

    wcvt_kernel<<<dim3(96), dim3(256), 0, stream>>>(Wq, Wk, Wv, Wb);
    qkv_kernel<<<dim3((B_ * T_) / 64), dim3(256), 0, stream>>>(
        x, Wb, bq, bk, bv, Qo, Ko, Vt);
    attn_kernel<<<dim3(512), dim3(256), 0, stream>>>(Qo, Ko, Vt, o);
}

// Round 17
// 246.328 us; speedup vs baseline: 1.1526x; 1.1526x over previous
//
#include <hip/hip_runtime.h>
#include <hip/hip_bf16.h>

typedef __attribute__((ext_vector_type(8))) short s8v;   // 8 x bf16 bits
typedef __attribute__((ext_vector_type(4))) short s4v;
typedef __attribute__((ext_vector_type(4))) float f4v;

#define B_   8
#define T_   4096
#define C_   1024
#define HS_  64
#define K2_  2048

__device__ __forceinline__ int keep_of(int i) {
    // keep[i] for i in [0,2048): exact integer version of the reference formula
    if (i >= 1024) return 2048 + i;
    int d = 1023 - i;
    return 3071 - ((3 * d * d + 1023) >> 10);
}

__device__ __forceinline__ short bf16_bits(float f) {
    union { __hip_bfloat16 h; short s; } u;
    u.h = __float2bfloat16(f);
    return u.s;
}

// load 8 consecutive fp32, round to bf16, pack into an MFMA bf16 fragment half
__device__ __forceinline__ s8v cvt8f(const float* p) {
    const f4v a = *(const f4v*)p;
    const f4v b = *(const f4v*)(p + 4);
    s8v r;
    r[0] = bf16_bits(a[0]); r[1] = bf16_bits(a[1]);
    r[2] = bf16_bits(a[2]); r[3] = bf16_bits(a[3]);
    r[4] = bf16_bits(b[0]); r[5] = bf16_bits(b[1]);
    r[6] = bf16_bits(b[2]); r[7] = bf16_bits(b[3]);
    return r;
}

// async 16B global -> LDS (direct-to-shared DMA; no VGPR round trip)
__device__ __forceinline__ void gload_lds16(const void* g, void* l) {
    __builtin_amdgcn_global_load_lds(
        (__attribute__((address_space(1))) void*)(g),
        (__attribute__((address_space(3))) void*)(l), 16, 0, 0);
}

// ------------- Kernel W: one-shot fp32 -> bf16 conversion of Wq/Wk/Wv -------
__global__ __launch_bounds__(256) void wcvt_kernel(
    const float* __restrict__ Wq, const float* __restrict__ Wk,
    const float* __restrict__ Wv, short* __restrict__ Wb)
{
    const int idx = (blockIdx.x * 256 + threadIdx.x) * 8;   // 0..196600
    const int mat = idx >> 16;                              // 0,1,2
    const int off = idx & 65535;
    const float* src = (mat == 0) ? Wq : (mat == 1) ? Wk : Wv;
    *(s8v*)(Wb + idx) = cvt8f(src + off);
}

// ---------------- Kernel A: fused QKV projection (R11 version) --------------
// Block = 64 token rows x 192 out-cols (Q|K|V), BK=64, 16 K-steps, 40KB LDS
// -> 4 blocks/CU; cross-block overlap hides the 2-barrier drain (m114).
// V output tiled [T/64][HS][64] per batch (contiguous 8KB per 64-token tile).
__global__ __launch_bounds__(256) void qkv_kernel(
    const float* __restrict__ x,
    const short* __restrict__ Wb,   // [192][1024] bf16 (Wq|Wk|Wv rows)
    const float* __restrict__ bq, const float* __restrict__ bk,
    const float* __restrict__ bv,
    __hip_bfloat16* __restrict__ Qo, __hip_bfloat16* __restrict__ Ko,
    __hip_bfloat16* __restrict__ Vt)
{
    __shared__ __align__(16) char smem[40960];
    float* xs  = (float*)smem;            // [64 rows][64 k] fp32, 256B rows
    short* wsm = (short*)(smem + 16384);  // [192 rows][64 k] bf16, 128B rows

    const int tid  = threadIdx.x;
    const int wave = tid >> 6;
    const int lane = tid & 63;
    const int l16  = lane & 15;
    const int quad = lane >> 4;
    const int row0 = blockIdx.x * 64;

    f4v acc[3][4];                        // [matrix][m-tile]
    #pragma unroll
    for (int m = 0; m < 3; ++m)
        #pragma unroll
        for (int mt = 0; mt < 4; ++mt) {
            acc[m][mt][0] = 0.f; acc[m][mt][1] = 0.f;
            acc[m][mt][2] = 0.f; acc[m][mt][3] = 0.f;
        }

    // staging geometry (lane-contiguous LDS dest; swizzle in global src)
    int xrow[4], xoff[4];
    #pragma unroll
    for (int i = 0; i < 4; ++i) {
        const int f = 256 * i + tid;
        xrow[i] = f >> 4;
        xoff[i] = ((f & 15) ^ (xrow[i] & 7)) * 4;    // floats
    }
    int wrow[6], woff[6];
    #pragma unroll
    for (int i = 0; i < 6; ++i) {
        const int f = 256 * i + tid;
        wrow[i] = f >> 3;
        woff[i] = ((f & 7) ^ (wrow[i] & 7)) * 8;     // shorts
    }

    for (int k0 = 0; k0 < C_; k0 += 64) {
        __syncthreads();                  // previous step's LDS reads done
        #pragma unroll
        for (int i = 0; i < 4; ++i)
            gload_lds16(x + (size_t)(row0 + xrow[i]) * C_ + k0 + xoff[i],
                        (char*)xs + (256 * i + tid) * 16);
        #pragma unroll
        for (int i = 0; i < 6; ++i)
            gload_lds16(Wb + (size_t)wrow[i] * C_ + k0 + woff[i],
                        (char*)wsm + (256 * i + tid) * 16);
        __syncthreads();                  // vmcnt(0) drain -> tiles visible

        #pragma unroll
        for (int kh = 0; kh < 2; ++kh) {
            // A fragments: 4 m-tiles, converted fp32->bf16 once per kh
            s8v a[4];
            #pragma unroll
            for (int mt = 0; mt < 4; ++mt) {
                const int r   = mt * 16 + l16;
                const int ch0 = kh * 8 + quad * 2;
                const float* p0 = xs + r * 64 + ((ch0    ) ^ (r & 7)) * 4;
                const float* p1 = xs + r * 64 + ((ch0 + 1) ^ (r & 7)) * 4;
                const f4v u = *(const f4v*)p0;
                const f4v v = *(const f4v*)p1;
                s8v af;
                af[0] = bf16_bits(u[0]); af[1] = bf16_bits(u[1]);
                af[2] = bf16_bits(u[2]); af[3] = bf16_bits(u[3]);
                af[4] = bf16_bits(v[0]); af[5] = bf16_bits(v[1]);
                af[6] = bf16_bits(v[2]); af[7] = bf16_bits(v[3]);
                a[mt] = af;
            }
            // B fragments + MFMA: 3 matrices
            #pragma unroll
            for (int m = 0; m < 3; ++m) {
                const int wr = m * 64 + wave * 16 + l16;     // W row
                const int ch = kh * 4 + quad;                // 16B chunk 0..7
                const s8v bf = *(const s8v*)(wsm + wr * 64 + ((ch ^ (wr & 7)) * 8));
                #pragma unroll
                for (int mt = 0; mt < 4; ++mt)
                    acc[m][mt] = __builtin_amdgcn_mfma_f32_16x16x32_bf16(a[mt], bf, acc[m][mt], 0, 0, 0);
            }
        }
    }

    // epilogue: C/D layout col = lane&15 (folded into wc), row = quad*4+reg
    const int wc = wave * 16 + l16;                  // output column 0..63
    const float bqv = bq[wc], bkv = bk[wc], bvv = bv[wc];
    #pragma unroll
    for (int mt = 0; mt < 4; ++mt) {
        const int rbase = row0 + mt * 16 + quad * 4; // global token row
        #pragma unroll
        for (int r = 0; r < 4; ++r) {
            Qo[(size_t)(rbase + r) * HS_ + wc] = __float2bfloat16(acc[0][mt][r] + bqv);
            Ko[(size_t)(rbase + r) * HS_ + wc] = __float2bfloat16(acc[1][mt][r] + bkv);
        }
        s4v vp;
        #pragma unroll
        for (int r = 0; r < 4; ++r) vp[r] = bf16_bits(acc[2][mt][r] + bvv);
        const int bb = rbase >> 12;                  // batch
        const int t  = rbase & (T_ - 1);             // token within batch
        // tiled V^T: [T/64 tiles][HS][64t], tile = contiguous 8KB
        *(s4v*)(Vt + (size_t)bb * HS_ * T_
                   + (size_t)(t & ~63) * HS_ + wc * 64 + (t & 63)) = vp;
    }
}

// ---------------- Kernel B: flash attention, merged-qb single sweep ---------
// Round 15: R13's merged-qb sweep with the rule-#20 fix — ALL e-indexed
// arrays (accO, l_p, aq, keepr) now accessed with COMPILE-TIME e only:
// main-loop break -> unrollable guard; epilogue loop fully unrolled. R14's
// `#pragma unroll 1` epilogue forced accO into scratch (WRITE_SIZE 89MB,
// VGPR 116) — the whole accumulator round-tripped through HBM per MFMA.
__global__ __launch_bounds__(256) void attn_kernel(
    const __hip_bfloat16* __restrict__ Qo,
    const __hip_bfloat16* __restrict__ Ko,
    const __hip_bfloat16* __restrict__ Vt,
    float* __restrict__ out)
{
    __shared__ __align__(16) char smem[73728];
    short* Ks = (short*)smem;                 // [256 t][64 d] swizzled, 32KB
    short* Vs = (short*)(smem + 32768);       // [4 tiles][64 d][64 t] swz, 32KB
    float* mL = (float*)smem;                 // epilogue overlay (Ks dead)
    float* mO = (float*)(smem + 256);

    const int b    = blockIdx.x & 7;          // XCD-affine batch
    const int pp   = 63 - (blockIdx.x >> 3);  // heavy pairs first
    const int tid  = threadIdx.x;
    const int wave = tid >> 6;
    const int lane = tid & 63;
    const int l16  = lane & 15;
    const int quad = lane >> 4;

    short* pw = (short*)(smem + 65536) + wave * 1024;   // wave-private P, 2KB

    const short* kb = (const short*)Ko + (size_t)b * T_ * HS_;
    const short* vb = (const short*)Vt + (size_t)b * HS_ * T_;

    // staging geometry (tid-const; global-source swizzle, linear LDS dest)
    int kgoff[8], vgoff[8];
    #pragma unroll
    for (int j = 0; j < 8; ++j) {
        const int ki = j * 256 + tid;         // 16B chunk index 0..2047
        const int kr = ki >> 3;               // K row (t) 0..255
        kgoff[j] = kr * 64 + (((tid & 7) ^ (kr & 7)) * 8);
        const int vs_ = ki >> 9;              // V sub-tile 0..3
        const int vd  = (ki & 511) >> 3;      // V row (d) 0..63
        vgoff[j] = (vs_ * 64 + vd) * 64 + (((tid & 7) ^ (vd & 7)) * 8);
    }

    const int qb1 = 64 + pp, qb2 = 63 - pp;   // qb1 has the longer t-range

    // Q fragments for both qb (A-operand): m = lane&15, k = quad*8+j
    s8v aq[2][2];
    int keepr[2][4], kmin[2], ntl[2];
    #pragma unroll
    for (int e = 0; e < 2; ++e) {
        const int qb = e ? qb2 : qb1;
        const int qt = keep_of(qb * 16 + l16);
        const __hip_bfloat16* qrow = Qo + ((size_t)(b * T_ + qt)) * HS_;
        aq[e][0] = *(const s8v*)(qrow + quad * 8);
        aq[e][1] = *(const s8v*)(qrow + 32 + quad * 8);
        #pragma unroll
        for (int r = 0; r < 4; ++r) keepr[e][r] = keep_of(qb * 16 + quad * 4 + r);
        kmin[e] = keep_of(qb * 16);
        ntl[e]  = (keep_of(qb * 16 + 15) >> 6) + 1;   // 64-wide t tiles
    }
    const int nsteps = (ntl[0] + 3) >> 2;             // ntl[0] >= ntl[1]

    f4v accO[2][4];
    float l_p[2][4];
    #pragma unroll
    for (int e = 0; e < 2; ++e)
        #pragma unroll
        for (int j = 0; j < 4; ++j) {
            accO[e][j][0]=0.f; accO[e][j][1]=0.f; accO[e][j][2]=0.f; accO[e][j][3]=0.f;
            l_p[e][j] = 0.f;
        }

    for (int s = 0; s < nsteps; ++s) {
        const int t064 = s << 14;             // (s*256)*64 shorts

        __syncthreads();                      // prev step's LDS reads done
        #pragma unroll
        for (int j = 0; j < 8; ++j)
            gload_lds16(kb + t064 + kgoff[j], (char*)smem + (j * 256 + tid) * 16);
        #pragma unroll
        for (int j = 0; j < 8; ++j)
            gload_lds16(vb + t064 + vgoff[j], (char*)smem + 32768 + (j * 256 + tid) * 16);
        __syncthreads();                      // vmcnt(0) drain -> tiles visible

        const int ttg = s * 4 + wave;         // this wave's tile index
        if (ttg < ntl[0]) {
            const int t0 = ttg << 6;

            // ---- K/V fragments: read ONCE, feed both qb ----
            s8v bk0[4], bk1[4], bv0[4], bv1[4];
            #pragma unroll
            for (int j = 0; j < 4; ++j) {
                const int row = wave * 64 + j * 16 + l16;
                bk0[j] = *(const s8v*)(Ks + row * 64 + (((quad    ) ^ (row & 7)) * 8));
                bk1[j] = *(const s8v*)(Ks + row * 64 + (((quad + 4) ^ (row & 7)) * 8));
                const int rd = j * 16 + l16;
                bv0[j] = *(const s8v*)(Vs + wave * 4096 + rd * 64 + (((quad    ) ^ (rd & 7)) * 8));
                bv1[j] = *(const s8v*)(Vs + wave * 4096 + rd * 64 + (((quad + 4) ^ (rd & 7)) * 8));
            }

            #pragma unroll
            for (int e = 0; e < 2; ++e) {
                // compile-time e; runtime guard instead of break (rule #20)
                if (e == 0 || ttg < ntl[1]) {
                    // ---- S = Q K^T ----
                    f4v s4[4];
                    #pragma unroll
                    for (int jn = 0; jn < 4; ++jn) {
                        f4v z; z[0]=0.f; z[1]=0.f; z[2]=0.f; z[3]=0.f;
                        z = __builtin_amdgcn_mfma_f32_16x16x32_bf16(aq[e][0], bk0[jn], z, 0, 0, 0);
                        z = __builtin_amdgcn_mfma_f32_16x16x32_bf16(aq[e][1], bk1[jn], z, 0, 0, 0);
                        s4[jn] = z;
                    }

                    // p = valid ? exp(s/32) : 0 ; mask only on boundary tiles
                    if (t0 + 63 <= kmin[e]) { // fully valid (common)
                        #pragma unroll
                        for (int jn = 0; jn < 4; ++jn) {
                            const int t = jn * 16 + l16;
                            const int chunk = t >> 3;
                            #pragma unroll
                            for (int r = 0; r < 4; ++r) {
                                const float p = __expf(s4[jn][r] * 0.03125f);
                                l_p[e][r] += p;
                                const int m = quad * 4 + r;
                                pw[m * 64 + ((chunk ^ (m & 7)) * 8) + (t & 7)] = bf16_bits(p);
                            }
                        }
                    } else {                  // boundary tile
                        #pragma unroll
                        for (int jn = 0; jn < 4; ++jn) {
                            const int t = jn * 16 + l16;
                            const int valid_t = t0 + t;
                            const int chunk = t >> 3;
                            #pragma unroll
                            for (int r = 0; r < 4; ++r) {
                                const float ex = __expf(s4[jn][r] * 0.03125f);
                                const float p = (valid_t <= keepr[e][r]) ? ex : 0.0f;
                                l_p[e][r] += p;
                                const int m = quad * 4 + r;
                                pw[m * 64 + ((chunk ^ (m & 7)) * 8) + (t & 7)] = bf16_bits(p);
                            }
                        }
                    }
                    const s8v ap0 = *(const s8v*)(pw + l16 * 64 + ((quad    ) ^ (l16 & 7)) * 8);
                    const s8v ap1 = *(const s8v*)(pw + l16 * 64 + ((quad + 4) ^ (l16 & 7)) * 8);

                    // ---- O += P V ----
                    #pragma unroll
                    for (int jd = 0; jd < 4; ++jd) {
                        accO[e][jd] = __builtin_amdgcn_mfma_f32_16x16x32_bf16(ap0, bv0[jd], accO[e][jd], 0, 0, 0);
                        accO[e][jd] = __builtin_amdgcn_mfma_f32_16x16x32_bf16(ap1, bv1[jd], accO[e][jd], 0, 0, 0);
                    }
                }
            }
        }
    }

    // ---- epilogue per qb: butterfly -> cross-wave merge -> normalize -> out
    // FULLY UNROLLED: every accO/l_p index is compile-time (rule #20 fix).
    #pragma unroll
    for (int e = 0; e < 2; ++e) {
        const int qb = e ? qb2 : qb1;
        #pragma unroll
        for (int off = 1; off < 16; off <<= 1)
            #pragma unroll
            for (int r = 0; r < 4; ++r) l_p[e][r] += __shfl_xor(l_p[e][r], off);

        __syncthreads();                      // K/V/P LDS (or prev mO) dead
        #pragma unroll
        for (int r = 0; r < 4; ++r) {
            const int row = quad * 4 + r;
            if (l16 == 0) mL[wave * 16 + row] = l_p[e][r];
            #pragma unroll
            for (int jd = 0; jd < 4; ++jd)
                mO[wave * 1024 + row * 64 + jd * 16 + l16] = accO[e][jd][r];
        }
        __syncthreads();

        {
            const int row = tid >> 4;         // 0..15
            const int col = (tid & 15) * 4;   // 0..60
            float L = 0.f;
            #pragma unroll
            for (int w = 0; w < 4; ++w) L += mL[w * 16 + row];
            const float inv = 1.0f / L;
            f4v o; o[0]=0.f; o[1]=0.f; o[2]=0.f; o[3]=0.f;
            #pragma unroll
            for (int w = 0; w < 4; ++w) {
                const f4v ow = *(const f4v*)(mO + w * 1024 + row * 64 + col);
                #pragma unroll
                for (int j = 0; j < 4; ++j) o[j] += ow[j];
            }
            #pragma unroll
            for (int j = 0; j < 4; ++j) o[j] *= inv;
            *(f4v*)(out + ((size_t)(b * K2_ + qb * 16 + row)) * HS_ + col) = o;
        }
    }
}

extern "C" void kernel_launch(void* const* d_in, const int* in_sizes, int n_in,
                              void* d_out, int out_size, void* d_ws, size_t ws_size,
                              hipStream_t stream) {
    (void)in_sizes; (void)n_in; (void)out_size; (void)ws_size;
    const float* x  = (const float*)d_in[0];
    const float* Wq = (const float*)d_in[1];
    const float* bq = (const float*)d_in[2];
    const float* Wk = (const float*)d_in[3];
    const float* bk = (const float*)d_in[4];
    const float* Wv = (const float*)d_in[5];
    const float* bv = (const float*)d_in[6];

    __hip_bfloat16* Qo = (__hip_bfloat16*)d_ws;                       // 4 MB
    __hip_bfloat16* Ko = Qo + (size_t)B_ * T_ * HS_;                  // 4 MB
    __hip_bfloat16* Vt = Ko + (size_t)B_ * T_ * HS_;                  // 4 MB (tiled)
    short*          Wb = (short*)(Vt + (size_t)B_ * HS_ * T_);        // 384 KB
    float* o = (float*)d_out;

    wcvt_kernel<<<dim3(96), dim3(256), 0, stream>>>(Wq, Wk, Wv, Wb);
    qkv_kernel<<<dim3((B_ * T_) / 64), dim3(256), 0, stream>>>(
        x, Wb, bq, bk, bv, Qo, Ko, Vt);
    attn_kernel<<<dim3(512), dim3(256), 0, stream>>>(Qo, Ko, Vt, o);
}